// Round 1
// baseline (493.267 us; speedup 1.0000x reference)
//
#include <hip/hip_runtime.h>

#define N_NODES 262144
#define N_VARS  65536
#define HID     256
#define NGRAPH  512

// ---- workspace layout (bytes); total ~2.44 MB ----
#define OFF_WBT   0u         // 256*256 bf16 (ushort)          = 131072
#define OFF_GATE  131072u    // 65536 f32                      = 262144
#define OFF_NODEW 393216u    // 262144 f32                     = 1048576
#define OFF_GSUM  1441792u   // 512*256 f32                    = 524288
#define OFF_GMAX  1966080u   // 512*256 u32 (ordered-key max)  = 524288
#define OFF_GCNT  2490368u   // 512 u32
#define OFF_CCNT  2492416u   // 256 u32
#define OFF_COFF  2493440u   // 256 u32

typedef float f32x4 __attribute__((ext_vector_type(4)));
typedef short s16x8 __attribute__((ext_vector_type(8)));

__device__ __forceinline__ unsigned short f2bf(float f) {
    unsigned u = __float_as_uint(f);
    unsigned r = u + 0x7fffu + ((u >> 16) & 1u);
    return (unsigned short)(r >> 16);
}

__device__ __forceinline__ unsigned fmax_key(float f) {
    unsigned u = __float_as_uint(f);
    return (u & 0x80000000u) ? ~u : (u | 0x80000000u);
}

// -------- pack W_pre [k][n] f32 -> wbt [n][k] bf16 --------
__global__ void k_pack(const float* __restrict__ W, unsigned short* __restrict__ wbt) {
    int n = blockIdx.x, k = threadIdx.x;
    wbt[n * 256 + k] = f2bf(W[k * 256 + n]);
}

// -------- gating MLP: gate[v] = sigmoid(relu(vpp @ W1 + b1) @ W2 + b2) --------
__global__ void k_gate(const float* __restrict__ vpp, const float* __restrict__ W1,
                       const float* __restrict__ b1, const float* __restrict__ W2,
                       const float* __restrict__ b2, float* __restrict__ gate) {
    __shared__ float sW1[512], sb1[64], sW2[64], sb2;
    int t = threadIdx.x;
    sW1[t] = W1[t];
    sW1[t + 256] = W1[t + 256];
    if (t < 64) { sb1[t] = b1[t]; sW2[t] = W2[t]; }
    if (t == 0) sb2 = b2[0];
    __syncthreads();
    int v = blockIdx.x * 256 + t;
    float4 p0 = ((const float4*)vpp)[v * 2];
    float4 p1 = ((const float4*)vpp)[v * 2 + 1];
    float p[8] = {p0.x, p0.y, p0.z, p0.w, p1.x, p1.y, p1.z, p1.w};
    float acc = sb2;
#pragma unroll 8
    for (int j = 0; j < 64; ++j) {
        float h = sb1[j];
#pragma unroll
        for (int q = 0; q < 8; ++q) h += p[q] * sW1[q * 64 + j];
        h = fmaxf(h, 0.f);
        acc += h * sW2[j];
    }
    gate[v] = 1.f / (1.f + expf(-acc));
}

// -------- count variable nodes per 1024-node chunk --------
__global__ void k_ccnt(const int* __restrict__ nt, unsigned* __restrict__ ccnt) {
    __shared__ unsigned s[256];
    int t = threadIdx.x;
    int4 v = ((const int4*)nt)[blockIdx.x * 256 + t];
    unsigned c = (unsigned)(v.x == 0) + (v.y == 0) + (v.z == 0) + (v.w == 0);
    s[t] = c;
    __syncthreads();
    for (int off = 128; off; off >>= 1) {
        if (t < off) s[t] += s[t + off];
        __syncthreads();
    }
    if (t == 0) ccnt[blockIdx.x] = s[0];
}

// -------- exclusive scan of 256 chunk counts --------
__global__ void k_scan(const unsigned* __restrict__ ccnt, unsigned* __restrict__ coff) {
    __shared__ unsigned s[256];
    int t = threadIdx.x;
    unsigned own = ccnt[t];
    s[t] = own;
    __syncthreads();
    for (int off = 1; off < 256; off <<= 1) {
        unsigned v = (t >= off) ? s[t - off] : 0u;
        __syncthreads();
        s[t] += v;
        __syncthreads();
    }
    coff[t] = s[t] - own;
}

// -------- node weights: var nodes get gate[rank], others 1.0 --------
__global__ void k_nodew(const int* __restrict__ nt, const unsigned* __restrict__ coff,
                        const float* __restrict__ gate, float* __restrict__ nodew) {
    __shared__ unsigned s[256];
    int t = threadIdx.x;
    int4 v = ((const int4*)nt)[blockIdx.x * 256 + t];
    unsigned m0 = (v.x == 0), m1 = (v.y == 0), m2 = (v.z == 0), m3 = (v.w == 0);
    unsigned c = m0 + m1 + m2 + m3;
    s[t] = c;
    __syncthreads();
    for (int off = 1; off < 256; off <<= 1) {
        unsigned u = (t >= off) ? s[t - off] : 0u;
        __syncthreads();
        s[t] += u;
        __syncthreads();
    }
    unsigned rank = coff[blockIdx.x] + s[t] - c;
    const unsigned cap = N_VARS - 1;
    float4 w;
    w.x = m0 ? gate[rank < cap ? rank : cap] : 1.f; rank += m0;
    w.y = m1 ? gate[rank < cap ? rank : cap] : 1.f; rank += m1;
    w.z = m2 ? gate[rank < cap ? rank : cap] : 1.f; rank += m2;
    w.w = m3 ? gate[rank < cap ? rank : cap] : 1.f;
    ((float4*)nodew)[blockIdx.x * 256 + t] = w;
}

// -------- per-graph node counts via binary search (batch sorted) --------
__global__ void k_gcnt(const int* __restrict__ batch, unsigned* __restrict__ gcnt) {
    int g = threadIdx.x;  // 512 threads
    int lo = 0, hi = N_NODES;
    while (lo < hi) { int mid = (lo + hi) >> 1; if (batch[mid] < g) lo = mid + 1; else hi = mid; }
    int lb0 = lo;
    lo = lb0; hi = N_NODES;
    while (lo < hi) { int mid = (lo + hi) >> 1; if (batch[mid] < g + 1) lo = mid + 1; else hi = mid; }
    gcnt[g] = (unsigned)(lo - lb0);
}

// -------- main fused kernel: h = (X @ W_pre + b_pre) * node_w; segment sum+max --------
// 64 rows/block, 256 threads (4 waves), wave w owns cols [w*64, w*64+64).
__global__ __launch_bounds__(256, 3) void k_main(
        const float* __restrict__ X, const int* __restrict__ batch,
        const float* __restrict__ nodew, const unsigned short* __restrict__ wbt,
        const float* __restrict__ bpre, float* __restrict__ gsum,
        unsigned* __restrict__ gmax) {
    // LDS: [0,32896) = union{ A bf16 64x256 swizzled (32768) | hlds f32 [32][257] (32896) }
    __shared__ __align__(16) unsigned char smem[34432];
    float* hlds  = (float*)smem;
    float* sbpre = (float*)(smem + 32896);  // 256 f32
    float* snw   = (float*)(smem + 33920);  // 64 f32
    int*   sbt   = (int*)(smem + 34176);    // 64 i32

    int t = threadIdx.x;
    int rowbase = blockIdx.x * 64;
    sbpre[t] = bpre[t];
    if (t < 64) { snw[t] = nodew[rowbase + t]; sbt[t] = batch[rowbase + t]; }

    // stage A: f32 -> bf16, XOR-swizzled rows (stride 512B)
#pragma unroll
    for (int i = 0; i < 16; ++i) {
        int idx = t + 256 * i;
        int r = idx >> 6, cg = idx & 63;
        float4 v = ((const float4*)X)[(rowbase + r) * 64 + cg];
        unsigned lo = (unsigned)f2bf(v.x) | ((unsigned)f2bf(v.y) << 16);
        unsigned hi = (unsigned)f2bf(v.z) | ((unsigned)f2bf(v.w) << 16);
        int byte = (r * 512 + cg * 8) ^ ((r & 7) << 4);
        *(uint2*)(smem + byte) = make_uint2(lo, hi);
    }
    __syncthreads();

    int wave = t >> 6, lane = t & 63;
    int colbase = wave * 64;
    f32x4 acc[4][4];
#pragma unroll
    for (int r = 0; r < 4; ++r)
#pragma unroll
        for (int c = 0; c < 4; ++c)
#pragma unroll
            for (int q = 0; q < 4; ++q) acc[r][c][q] = 0.f;

    const unsigned short* wp[4];
#pragma unroll
    for (int c = 0; c < 4; ++c)
        wp[c] = wbt + (colbase + c * 16 + (lane & 15)) * 256 + ((lane >> 4) * 8);

#pragma unroll
    for (int kk = 0; kk < 8; ++kk) {
        s16x8 a[4], b[4];
#pragma unroll
        for (int r = 0; r < 4; ++r) {
            int row = r * 16 + (lane & 15);
            int byte = (row * 512 + (kk * 32 + (lane >> 4) * 8) * 2) ^ ((row & 7) << 4);
            a[r] = *(const s16x8*)(smem + byte);
        }
#pragma unroll
        for (int c = 0; c < 4; ++c) b[c] = *(const s16x8*)(wp[c] + kk * 32);
#pragma unroll
        for (int r = 0; r < 4; ++r)
#pragma unroll
            for (int c = 0; c < 4; ++c)
                asm volatile("v_mfma_f32_16x16x32_bf16 %0, %1, %2, %0"
                             : "+v"(acc[r][c]) : "v"(a[r]), "v"(b[c]));
    }
    asm volatile("s_nop 7\n\ts_nop 7\n\ts_nop 7" ::);
    __syncthreads();  // all A reads done; smem becomes hlds

    float sum = 0.f, mx = -3.4e38f;
    int g = sbt[0];
    auto flush = [&]() {
        atomicAdd(&gsum[g * 256 + t], sum);
        atomicMax(&gmax[g * 256 + t], fmax_key(mx));
    };

#pragma unroll
    for (int ph = 0; ph < 2; ++ph) {
        // write h for rows [ph*32, ph*32+32)
#pragma unroll
        for (int r = 2 * ph; r < 2 * ph + 2; ++r) {
            int row0 = r * 16 + (lane >> 4) * 4;
#pragma unroll
            for (int c = 0; c < 4; ++c) {
                int col = colbase + c * 16 + (lane & 15);
                float bp = sbpre[col];
#pragma unroll
                for (int j = 0; j < 4; ++j) {
                    float vv = (acc[r][c][j] + bp) * snw[row0 + j];
                    hlds[(row0 + j - ph * 32) * 257 + col] = vv;
                }
            }
        }
        __syncthreads();
        // column-walk segment reduction (thread t = column)
        for (int r = 0; r < 32; ++r) {
            int gg = sbt[ph * 32 + r];
            if (gg != g) { flush(); sum = 0.f; mx = -3.4e38f; g = gg; }
            float vv = hlds[r * 257 + t];
            sum += vv;
            mx = fmaxf(mx, vv);
        }
        __syncthreads();  // before next phase overwrites hlds
    }
    flush();
}

// -------- final: out[g] = concat(mean, max) @ W_post + b_post --------
__global__ void k_final(const float* __restrict__ gsum, const unsigned* __restrict__ gmax,
                        const unsigned* __restrict__ gcnt, const float* __restrict__ Wp,
                        const float* __restrict__ bp, float* __restrict__ out) {
    __shared__ float hrow[512];
    int g = blockIdx.x, j = threadIdx.x;
    unsigned cnt = gcnt[g];
    float inv = 1.f / (float)(cnt > 0u ? cnt : 1u);
    hrow[j] = gsum[g * 256 + j] * inv;
    unsigned key = gmax[g * 256 + j];
    float m = 0.f;
    if (cnt != 0u) {
        unsigned u = (key & 0x80000000u) ? (key ^ 0x80000000u) : ~key;
        m = __uint_as_float(u);
    }
    hrow[256 + j] = m;
    __syncthreads();
    float accv = bp[j];
#pragma unroll 8
    for (int k = 0; k < 512; ++k) accv += hrow[k] * Wp[k * 256 + j];
    out[g * 256 + j] = accv;
}

extern "C" void kernel_launch(void* const* d_in, const int* in_sizes, int n_in,
                              void* d_out, int out_size, void* d_ws, size_t ws_size,
                              hipStream_t stream) {
    const float* X      = (const float*)d_in[0];
    const int*   batch  = (const int*)d_in[1];
    const float* vpp    = (const float*)d_in[2];
    const int*   nt     = (const int*)d_in[3];
    const float* W_pre  = (const float*)d_in[4];
    const float* b_pre  = (const float*)d_in[5];
    const float* W1     = (const float*)d_in[6];
    const float* b1     = (const float*)d_in[7];
    const float* W2     = (const float*)d_in[8];
    const float* b2     = (const float*)d_in[9];
    const float* W_post = (const float*)d_in[10];
    const float* b_post = (const float*)d_in[11];
    float* out = (float*)d_out;

    char* ws = (char*)d_ws;
    unsigned short* wbt = (unsigned short*)(ws + OFF_WBT);
    float* gate  = (float*)(ws + OFF_GATE);
    float* nodew = (float*)(ws + OFF_NODEW);
    float* gsum  = (float*)(ws + OFF_GSUM);
    unsigned* gmax = (unsigned*)(ws + OFF_GMAX);
    unsigned* gcnt = (unsigned*)(ws + OFF_GCNT);
    unsigned* ccnt = (unsigned*)(ws + OFF_CCNT);
    unsigned* coff = (unsigned*)(ws + OFF_COFF);

    // zero the atomic accumulators (gsum + gmax are contiguous)
    hipMemsetAsync(ws + OFF_GSUM, 0, 524288u * 2, stream);

    k_pack<<<256, 256, 0, stream>>>(W_pre, wbt);
    k_gate<<<256, 256, 0, stream>>>(vpp, W1, b1, W2, b2, gate);
    k_ccnt<<<256, 256, 0, stream>>>(nt, ccnt);
    k_scan<<<1, 256, 0, stream>>>(ccnt, coff);
    k_nodew<<<256, 256, 0, stream>>>(nt, coff, gate, nodew);
    k_gcnt<<<1, 512, 0, stream>>>(batch, gcnt);
    k_main<<<N_NODES / 64, 256, 0, stream>>>(X, batch, nodew, wbt, b_pre, gsum, gmax);
    k_final<<<NGRAPH, 256, 0, stream>>>(gsum, gmax, gcnt, W_post, b_post, out);
}

// Round 2
// 468.192 us; speedup vs baseline: 1.0536x; 1.0536x over previous
//
#include <hip/hip_runtime.h>

#define N_NODES 262144
#define N_VARS  65536
#define HID     256
#define NGRAPH  512

// ---- workspace layout (bytes) ----
#define OFF_WBT   0u         // 256*256 bf16 (ushort)   = 131072
#define OFF_GATE  131072u    // 65536 f32               = 262144
#define OFF_NODEW 393216u    // 262144 f32              = 1048576
#define OFF_GST   1441792u   // 513 u32 (graph starts)  -> pad 2560
#define OFF_CCNT  1444352u   // 256 u32
#define OFF_COFF  1445376u   // 256 u32

typedef float f32x4 __attribute__((ext_vector_type(4)));
typedef short s16x8 __attribute__((ext_vector_type(8)));

#define BAR() asm volatile("s_waitcnt lgkmcnt(0)\n\ts_barrier" ::: "memory")

__device__ __forceinline__ unsigned short f2bf(float f) {
    unsigned u = __float_as_uint(f);
    unsigned r = u + 0x7fffu + ((u >> 16) & 1u);
    return (unsigned short)(r >> 16);
}

// ---- fused prologue: pack W_pre, gating MLP, chunk var-counts, graph bounds ----
__global__ void k_pre(const float* __restrict__ W, const float* __restrict__ vpp,
                      const float* __restrict__ W1, const float* __restrict__ b1,
                      const float* __restrict__ W2, const float* __restrict__ b2,
                      const int* __restrict__ nt, const int* __restrict__ batch,
                      unsigned short* __restrict__ wbt, float* __restrict__ gate,
                      unsigned* __restrict__ ccnt, unsigned* __restrict__ gst) {
    __shared__ float sm[664];  // gate: 512 W1 + 64 b1 + 64 W2 + 1 b2; ccnt: 256
    int b = blockIdx.x, t = threadIdx.x;

    if (b < 256) {  // pack W_pre [k][n] f32 -> [n][k] bf16
        wbt[b * 256 + t] = f2bf(W[t * 256 + b]);
        return;
    }
    if (b < 512) {  // gating MLP
        float* sW1 = sm; float* sb1 = sm + 512; float* sW2 = sm + 576; float* sb2 = sm + 640;
        sW1[t] = W1[t];
        sW1[t + 256] = W1[t + 256];
        if (t < 64) { sb1[t] = b1[t]; sW2[t] = W2[t]; }
        if (t == 0) sb2[0] = b2[0];
        __syncthreads();
        int v = (b - 256) * 256 + t;
        float4 p0 = ((const float4*)vpp)[v * 2];
        float4 p1 = ((const float4*)vpp)[v * 2 + 1];
        float p[8] = {p0.x, p0.y, p0.z, p0.w, p1.x, p1.y, p1.z, p1.w};
        float acc = sb2[0];
#pragma unroll 8
        for (int j = 0; j < 64; ++j) {
            float h = sb1[j];
#pragma unroll
            for (int q = 0; q < 8; ++q) h += p[q] * sW1[q * 64 + j];
            h = fmaxf(h, 0.f);
            acc += h * sW2[j];
        }
        gate[v] = 1.f / (1.f + expf(-acc));
        return;
    }
    if (b < 768) {  // var-node count per 1024-node chunk
        unsigned* s = (unsigned*)sm;
        int chunk = b - 512;
        int4 v = ((const int4*)nt)[chunk * 256 + t];
        unsigned c = (unsigned)(v.x == 0) + (v.y == 0) + (v.z == 0) + (v.w == 0);
        s[t] = c;
        __syncthreads();
        for (int off = 128; off; off >>= 1) {
            if (t < off) s[t] += s[t + off];
            __syncthreads();
        }
        if (t == 0) ccnt[chunk] = s[0];
        return;
    }
    // b in {768, 769}: graph start boundaries via lower_bound on sorted batch
    int g = (b - 768) * 256 + t;
    int lo = 0, hi = N_NODES;
    while (lo < hi) { int mid = (lo + hi) >> 1; if (batch[mid] < g) lo = mid + 1; else hi = mid; }
    gst[g] = (unsigned)lo;
    if (g == 0) gst[NGRAPH] = N_NODES;
}

// ---- exclusive scan of 256 chunk counts ----
__global__ void k_scan(const unsigned* __restrict__ ccnt, unsigned* __restrict__ coff) {
    __shared__ unsigned s[256];
    int t = threadIdx.x;
    unsigned own = ccnt[t];
    s[t] = own;
    __syncthreads();
    for (int off = 1; off < 256; off <<= 1) {
        unsigned v = (t >= off) ? s[t - off] : 0u;
        __syncthreads();
        s[t] += v;
        __syncthreads();
    }
    coff[t] = s[t] - own;
}

// ---- node weights: var nodes get gate[rank], others 1.0 ----
__global__ void k_nodew(const int* __restrict__ nt, const unsigned* __restrict__ coff,
                        const float* __restrict__ gate, float* __restrict__ nodew) {
    __shared__ unsigned s[256];
    int t = threadIdx.x;
    int4 v = ((const int4*)nt)[blockIdx.x * 256 + t];
    unsigned m0 = (v.x == 0), m1 = (v.y == 0), m2 = (v.z == 0), m3 = (v.w == 0);
    unsigned c = m0 + m1 + m2 + m3;
    s[t] = c;
    __syncthreads();
    for (int off = 1; off < 256; off <<= 1) {
        unsigned u = (t >= off) ? s[t - off] : 0u;
        __syncthreads();
        s[t] += u;
        __syncthreads();
    }
    unsigned rank = coff[blockIdx.x] + s[t] - c;
    const unsigned cap = N_VARS - 1;
    float4 w;
    w.x = m0 ? gate[rank < cap ? rank : cap] : 1.f; rank += m0;
    w.y = m1 ? gate[rank < cap ? rank : cap] : 1.f; rank += m1;
    w.z = m2 ? gate[rank < cap ? rank : cap] : 1.f; rank += m2;
    w.w = m3 ? gate[rank < cap ? rank : cap] : 1.f;
    ((float4*)nodew)[blockIdx.x * 256 + t] = w;
}

// ---- fused main: one graph per block; GEMM tiles + segment mean/max + W_post GEMV ----
// 256 threads (4 waves); wave w owns output cols [w*64, w*64+64).
__global__ __launch_bounds__(256, 2) void k_main2(
        const float* __restrict__ X, const float* __restrict__ nodew,
        const unsigned short* __restrict__ wbt, const float* __restrict__ bpre,
        const unsigned* __restrict__ gst, const float* __restrict__ Wpost,
        const float* __restrict__ bpost, float* __restrict__ out) {
    // [0,32896) = union{ A bf16 64x256 swizzled (32768) | hlds f32 [32][257] (32896) }
    __shared__ __align__(16) unsigned char smem[36224];
    float* hlds  = (float*)smem;
    float* sbpre = (float*)(smem + 32896);  // 256 f32
    float* snw   = (float*)(smem + 33920);  // 64 f32
    float* hcomb = (float*)(smem + 34176);  // 512 f32

    int t = threadIdx.x;
    int g = blockIdx.x;
    int rs = (int)gst[g], re = (int)gst[g + 1];
    sbpre[t] = bpre[t];

    int wave = t >> 6, lane = t & 63;
    int colbase = wave * 64;
    const unsigned short* wp[4];
#pragma unroll
    for (int c = 0; c < 4; ++c)
        wp[c] = wbt + (colbase + c * 16 + (lane & 15)) * 256 + ((lane >> 4) * 8);

    float sumc = 0.f, maxc = -3.4e38f;

    // preload tile 0 into registers
    float4 pre[16];
#pragma unroll
    for (int i = 0; i < 16; ++i) {
        int idx = t + 256 * i;
        int r = idx >> 6, cg = idx & 63;
        int row = rs + r;
        pre[i] = (row < re) ? ((const float4*)X)[row * 64 + cg] : make_float4(0.f, 0.f, 0.f, 0.f);
    }

    for (int tb = rs; tb < re; tb += 64) {
        // convert + XOR-swizzled LDS store (A tile)
#pragma unroll
        for (int i = 0; i < 16; ++i) {
            int idx = t + 256 * i;
            int r = idx >> 6, cg = idx & 63;
            unsigned lo = (unsigned)f2bf(pre[i].x) | ((unsigned)f2bf(pre[i].y) << 16);
            unsigned hi = (unsigned)f2bf(pre[i].z) | ((unsigned)f2bf(pre[i].w) << 16);
            int byte = (r * 512 + cg * 8) ^ ((r & 7) << 4);
            *(uint2*)(smem + byte) = make_uint2(lo, hi);
        }
        if (t < 64) snw[t] = (tb + t < re) ? nodew[tb + t] : 0.f;
        BAR();

        // prefetch next tile (vmcnt stays in flight across hand barriers)
        if (tb + 64 < re) {
#pragma unroll
            for (int i = 0; i < 16; ++i) {
                int idx = t + 256 * i;
                int r = idx >> 6, cg = idx & 63;
                int row = tb + 64 + r;
                pre[i] = (row < re) ? ((const float4*)X)[row * 64 + cg]
                                    : make_float4(0.f, 0.f, 0.f, 0.f);
            }
        }

        // MFMA: 64 rows x 256 cols, K=256
        f32x4 acc[4][4];
#pragma unroll
        for (int r = 0; r < 4; ++r)
#pragma unroll
            for (int c = 0; c < 4; ++c)
#pragma unroll
                for (int q = 0; q < 4; ++q) acc[r][c][q] = 0.f;

#pragma unroll
        for (int kk = 0; kk < 8; ++kk) {
            s16x8 a[4], b[4];
#pragma unroll
            for (int r = 0; r < 4; ++r) {
                int row = r * 16 + (lane & 15);
                int byte = (row * 512 + (kk * 32 + (lane >> 4) * 8) * 2) ^ ((row & 7) << 4);
                a[r] = *(const s16x8*)(smem + byte);
            }
#pragma unroll
            for (int c = 0; c < 4; ++c) b[c] = *(const s16x8*)(wp[c] + kk * 32);
#pragma unroll
            for (int r = 0; r < 4; ++r)
#pragma unroll
                for (int c = 0; c < 4; ++c)
                    asm volatile("v_mfma_f32_16x16x32_bf16 %0, %1, %2, %0"
                                 : "+v"(acc[r][c]) : "v"(a[r]), "v"(b[c]));
        }
        asm volatile("s_nop 7\n\ts_nop 7\n\ts_nop 7" ::);
        BAR();  // all A-tile LDS reads drained; smem becomes hlds

        int rem = re - tb; if (rem > 64) rem = 64;
#pragma unroll
        for (int ph = 0; ph < 2; ++ph) {
            // write h for rows [ph*32, ph*32+32)
#pragma unroll
            for (int r = 2 * ph; r < 2 * ph + 2; ++r) {
                int row0 = r * 16 + (lane >> 4) * 4;
#pragma unroll
                for (int c = 0; c < 4; ++c) {
                    int col = colbase + c * 16 + (lane & 15);
                    float bp = sbpre[col];
#pragma unroll
                    for (int j = 0; j < 4; ++j) {
                        float vv = (acc[r][c][j] + bp) * snw[row0 + j];
                        hlds[(row0 + j - ph * 32) * 257 + col] = vv;
                    }
                }
            }
            BAR();
            // column-walk reduction: thread t = column t; all rows same graph
            int rlim = rem - ph * 32;
            if (rlim > 32) rlim = 32;
            for (int r = 0; r < rlim; ++r) {
                float vv = hlds[r * 257 + t];
                sumc += vv;
                maxc = fmaxf(maxc, vv);
            }
            BAR();  // hlds reads done (also protects next tile's A staging)
        }
    }

    // finalize: mean/max -> hcomb[512], then out[g] = hcomb @ W_post + b_post
    int count = re - rs;
    float mean = (count > 0) ? sumc / (float)count : 0.f;
    float mx   = (count > 0) ? maxc : 0.f;
    hcomb[t] = mean;
    hcomb[256 + t] = mx;
    BAR();
    float accv = bpost[t];
#pragma unroll 8
    for (int k = 0; k < 512; ++k) accv += hcomb[k] * Wpost[k * 256 + t];
    out[g * 256 + t] = accv;
}

extern "C" void kernel_launch(void* const* d_in, const int* in_sizes, int n_in,
                              void* d_out, int out_size, void* d_ws, size_t ws_size,
                              hipStream_t stream) {
    const float* X      = (const float*)d_in[0];
    const int*   batch  = (const int*)d_in[1];
    const float* vpp    = (const float*)d_in[2];
    const int*   nt     = (const int*)d_in[3];
    const float* W_pre  = (const float*)d_in[4];
    const float* b_pre  = (const float*)d_in[5];
    const float* W1     = (const float*)d_in[6];
    const float* b1     = (const float*)d_in[7];
    const float* W2     = (const float*)d_in[8];
    const float* b2     = (const float*)d_in[9];
    const float* W_post = (const float*)d_in[10];
    const float* b_post = (const float*)d_in[11];
    float* out = (float*)d_out;

    char* ws = (char*)d_ws;
    unsigned short* wbt = (unsigned short*)(ws + OFF_WBT);
    float* gate  = (float*)(ws + OFF_GATE);
    float* nodew = (float*)(ws + OFF_NODEW);
    unsigned* gst  = (unsigned*)(ws + OFF_GST);
    unsigned* ccnt = (unsigned*)(ws + OFF_CCNT);
    unsigned* coff = (unsigned*)(ws + OFF_COFF);

    k_pre<<<770, 256, 0, stream>>>(W_pre, vpp, W1, b1, W2, b2, nt, batch,
                                   wbt, gate, ccnt, gst);
    k_scan<<<1, 256, 0, stream>>>(ccnt, coff);
    k_nodew<<<256, 256, 0, stream>>>(nt, coff, gate, nodew);
    k_main2<<<NGRAPH, 256, 0, stream>>>(X, nodew, wbt, b_pre, gst, W_post, b_post, out);
}